// Round 2
// baseline (449.543 us; speedup 1.0000x reference)
//
#include <hip/hip_runtime.h>
#include <math.h>

#define N_EMBED   2048
#define N_EXPERTS 64
#define TOP_K     8
#define TM        32     // tokens per block
#define TW        8      // tokens per wave
#define KC        64     // K-chunk staged in LDS

__global__ __launch_bounds__(256, 2)
void noisy_topk_kernel(const float* __restrict__ x,
                       const float* __restrict__ Wl, const float* __restrict__ bl,
                       const float* __restrict__ Wn, const float* __restrict__ bn,
                       float* __restrict__ out, int n_tokens) {
    __shared__ double Wd[N_EXPERTS][KC + 1];     // 33,280 B  combined weights (fp64, exact)
    __shared__ double nz[TM][N_EXPERTS + 1];     // 16,640 B  noisy logits / probs
    __shared__ float  idxs[TM][TOP_K];           //  1,024 B

    const int tid  = threadIdx.x;
    const int lane = tid & 63;
    const int wave = tid >> 6;
    const int t0   = blockIdx.x * TM;

    double acc[TW];
#pragma unroll
    for (int t = 0; t < TW; ++t) acc[t] = 0.0;

    const double myb = (double)bl[lane] + (double)bn[lane];

    for (int kc = 0; kc < N_EMBED; kc += KC) {
        // ---- stage combined W chunk as fp64: 64 rows x KC, coalesced reads ----
#pragma unroll
        for (int i = 0; i < (N_EXPERTS * KC / 4) / 256; ++i) {   // 4 float4 per thread
            int f  = tid + i * 256;
            int e  = f >> 4;            // KC/4 = 16 float4 per row
            int c4 = f & 15;
            const float4 a = *reinterpret_cast<const float4*>(&Wl[(size_t)e * N_EMBED + kc + c4 * 4]);
            const float4 b = *reinterpret_cast<const float4*>(&Wn[(size_t)e * N_EMBED + kc + c4 * 4]);
            Wd[e][c4 * 4 + 0] = (double)a.x + (double)b.x;
            Wd[e][c4 * 4 + 1] = (double)a.y + (double)b.y;
            Wd[e][c4 * 4 + 2] = (double)a.z + (double)b.z;
            Wd[e][c4 * 4 + 3] = (double)a.w + (double)b.w;
        }
        __syncthreads();

        // ---- compute: lane = expert, 8 tokens per wave, fp64 accumulate ----
        const float* xw = x + (size_t)(t0 + wave * TW) * N_EMBED + kc;
#pragma unroll 2
        for (int k = 0; k < KC; k += 4) {
            const double w0 = Wd[lane][k + 0];
            const double w1 = Wd[lane][k + 1];
            const double w2 = Wd[lane][k + 2];
            const double w3 = Wd[lane][k + 3];
#pragma unroll
            for (int t = 0; t < TW; ++t) {
                const float4 x4 = *reinterpret_cast<const float4*>(&xw[(size_t)t * N_EMBED + k]);
                acc[t] = fma((double)x4.x, w0, acc[t]);
                acc[t] = fma((double)x4.y, w1, acc[t]);
                acc[t] = fma((double)x4.z, w2, acc[t]);
                acc[t] = fma((double)x4.w, w3, acc[t]);
            }
        }
        __syncthreads();
    }

    // ---- noisy logits into LDS: nz[token][expert] (fp64) ----
#pragma unroll
    for (int t = 0; t < TW; ++t)
        nz[wave * TW + t][lane] = acc[t] + myb;
    __syncthreads();

    // ---- per-token top-8 + softmax in fp64 (threads 0..31) ----
    if (tid < TM) {
        double vals[TOP_K]; int vidx[TOP_K];
#pragma unroll
        for (int j = 0; j < TOP_K; ++j) { vals[j] = -INFINITY; vidx[j] = -1; }
        for (int e = 0; e < N_EXPERTS; ++e) {
            double cv = nz[tid][e]; int ci = e;
#pragma unroll
            for (int j = 0; j < TOP_K; ++j) {
                // strict > : ties keep the earlier (lower) index ahead (lax.top_k)
                bool sw = cv > vals[j];
                double tv = sw ? vals[j] : cv;
                int    ti = sw ? vidx[j] : ci;
                vals[j] = sw ? cv : vals[j];
                vidx[j] = sw ? ci : vidx[j];
                cv = tv; ci = ti;
            }
        }
        double m = vals[0];
        double s = 0.0;
        double p[TOP_K];
#pragma unroll
        for (int j = 0; j < TOP_K; ++j) { p[j] = exp(vals[j] - m); s += p[j]; }
        double inv = 1.0 / s;

#pragma unroll
        for (int e = 0; e < N_EXPERTS; ++e) nz[tid][e] = 0.0;
#pragma unroll
        for (int j = 0; j < TOP_K; ++j) {
            nz[tid][vidx[j]] = p[j] * inv;
            idxs[tid][j] = (float)vidx[j];
        }
    }
    __syncthreads();

    // ---- coalesced output writes ----
    float* out_router = out;
    float* out_idx    = out + (size_t)n_tokens * N_EXPERTS;
#pragma unroll
    for (int i = 0; i < (TM * N_EXPERTS) / 256; ++i) {   // 8 per thread
        int flat = tid + i * 256;
        int t = flat >> 6, e = flat & 63;
        out_router[(size_t)(t0 + t) * N_EXPERTS + e] = (float)nz[t][e];
    }
    {
        int t = tid >> 3, j = tid & 7;
        if (tid < TM * TOP_K)
            out_idx[(size_t)(t0 + t) * TOP_K + j] = idxs[t][j];
    }
}

extern "C" void kernel_launch(void* const* d_in, const int* in_sizes, int n_in,
                              void* d_out, int out_size, void* d_ws, size_t ws_size,
                              hipStream_t stream) {
    const float* x  = (const float*)d_in[0];
    const float* Wl = (const float*)d_in[1];
    const float* bl = (const float*)d_in[2];
    const float* Wn = (const float*)d_in[3];
    const float* bn = (const float*)d_in[4];
    float* out = (float*)d_out;

    int n_tokens = in_sizes[0] / N_EMBED;          // 16384
    int grid = (n_tokens + TM - 1) / TM;           // 512

    hipLaunchKernelGGL(noisy_topk_kernel, dim3(grid), dim3(256), 0, stream,
                       x, Wl, bl, Wn, bn, out, n_tokens);
}